// Round 5
// baseline (220.119 us; speedup 1.0000x reference)
//
#include <hip/hip_runtime.h>
#include <hip/hip_bf16.h>
#include <stdint.h>

// Workload (fixed):
//   x:            [B=32, L=4096, D=768] f32 (shape only)
//   topic_vectors:[T=2048, D=768] f32
//   out:          [B, L, T] f32 -- 1 GiB, batch-broadcast of a [L,T] 0/1 map.
// softmax monotone -> top_k(softmax(tv)) idx == top_k(tv) idx; idx < D=768 so
// `% L` is identity -> rows l >= 768 all zero. Only 2048*16 = 32768 ones.
//
// Strategy: bulk zeros via hipMemsetAsync (rocclr fillBufferAligned sustains
// ~6.6 TB/s, proven in profile) + sparse rewrite of only the 128-B output
// lines that contain a one (line == 32 topics == one bitmap word; ~49% of
// words nonzero -> ~105 MB rewritten instead of 215 MB, zero RMW).

#define B_DIM    32
#define L_DIM    4096
#define D_DIM    768
#define T_TOPICS 2048
#define K_TOP    16

#define WORDS_PER_ROW (T_TOPICS / 32)            // 64 u32 per l-row
#define BITMAP_WORDS  (D_DIM * WORDS_PER_ROW)    // 49152 words = 192 KiB
#define PLANE_F  (L_DIM * T_TOPICS)              // floats per batch plane

typedef float f32x4 __attribute__((ext_vector_type(4)));

__global__ void zero_bitmap_kernel(uint32_t* __restrict__ bm) {
    int i = blockIdx.x * blockDim.x + threadIdx.x;
    if (i < BITMAP_WORDS) bm[i] = 0u;
}

// One wave per topic; 16x wave-argmax (tie -> smaller index, = jax top_k),
// set bit (l=idx, t=topic) in the [D_DIM][T_TOPICS] bitmap.
__global__ void topk_kernel(const float* __restrict__ tv, uint32_t* __restrict__ bm) {
    const int t    = blockIdx.x;
    const int lane = threadIdx.x;
    const float* __restrict__ row = tv + (size_t)t * D_DIM;

    float v[D_DIM / 64];                 // 12 values, idx = lane + j*64
    #pragma unroll
    for (int j = 0; j < D_DIM / 64; ++j) v[j] = row[lane + j * 64];

    for (int k = 0; k < K_TOP; ++k) {
        float bv = v[0];
        int   bj = 0;
        #pragma unroll
        for (int j = 1; j < D_DIM / 64; ++j) {
            if (v[j] > bv) { bv = v[j]; bj = j; }
        }
        float cv = bv;
        int   ci = lane + bj * 64;
        #pragma unroll
        for (int off = 32; off > 0; off >>= 1) {
            float ov = __shfl_xor(cv, off);
            int   oi = __shfl_xor(ci, off);
            if (ov > cv || (ov == cv && oi < ci)) { cv = ov; ci = oi; }
        }
        if ((ci & 63) == lane) v[ci >> 6] = -INFINITY;
        if (lane == 0) {
            atomicOr(&bm[ci * WORDS_PER_ROW + (t >> 5)], 1u << (t & 31));
        }
    }
}

// Sparse rewrite after the bulk memset. One wave handles 8 bitmap words
// (8 x 128-B output lines) of one (l, b): lane i -> word wg8*8 + (i>>3),
// slice s = i&7 covers topics [word*32 + s*4, +4) = one dwordx4.
// An 8-lane group stores its full 128-B line only if its word != 0
// (w is uniform within the group -> exec-masked, full lines, no RMW).
// b is the slowest index so consecutive waves write consecutive addresses.
__global__ __launch_bounds__(256) void rewrite_kernel(const uint32_t* __restrict__ bm,
                                                      float* __restrict__ out) {
    const unsigned W    = blockIdx.x * 4u + (threadIdx.x >> 6);  // global wave id
    const unsigned lane = threadIdx.x & 63u;
    const unsigned wg8  = W & 7u;            // which 8-word group of the row
    const unsigned r    = W >> 3;            // 0 .. 768*32-1
    const unsigned l    = r % (unsigned)D_DIM;
    const unsigned b    = r / (unsigned)D_DIM;

    const unsigned word_idx = wg8 * 8u + (lane >> 3);            // 0..63
    const uint32_t w = bm[l * WORDS_PER_ROW + word_idx];
    if (w != 0u) {
        const unsigned s    = lane & 7u;
        const unsigned bits = (w >> (s * 4u)) & 0xFu;
        f32x4 val;
        val.x = (bits & 1u) ? 1.0f : 0.0f;
        val.y = (bits & 2u) ? 1.0f : 0.0f;
        val.z = (bits & 4u) ? 1.0f : 0.0f;
        val.w = (bits & 8u) ? 1.0f : 0.0f;
        float* p = out + (size_t)b * PLANE_F + (size_t)l * T_TOPICS
                       + word_idx * 32u + s * 4u;
        *(f32x4*)p = val;
    }
}

extern "C" void kernel_launch(void* const* d_in, const int* in_sizes, int n_in,
                              void* d_out, int out_size, void* d_ws, size_t ws_size,
                              hipStream_t stream) {
    const float* tv  = (const float*)d_in[1];   // topic_vectors [T, D]
    float*       out = (float*)d_out;           // [B, L, T] f32
    uint32_t*    bm  = (uint32_t*)d_ws;         // 192 KiB bitmap

    hipLaunchKernelGGL(zero_bitmap_kernel,
                       dim3((BITMAP_WORDS + 255) / 256), dim3(256), 0, stream, bm);
    hipLaunchKernelGGL(topk_kernel,
                       dim3(T_TOPICS), dim3(64), 0, stream, tv, bm);

    // Bulk zeros through the rocclr fast-fill path (~6.6 TB/s measured).
    hipMemsetAsync(d_out, 0, (size_t)out_size * sizeof(float), stream);

    // Waves: 8 per (l, b) row-half-group -> 768*32*8 / 4 waves per block.
    const unsigned total_waves = (unsigned)D_DIM * B_DIM * 8u;   // 196,608
    hipLaunchKernelGGL(rewrite_kernel,
                       dim3(total_waves / 4), dim3(256), 0, stream, bm, out);
}